// Round 11
// baseline (387.962 us; speedup 1.0000x reference)
//
#include <hip/hip_runtime.h>
#include <stdint.h>

// Problem constants (match reference)
#define B_TOT 4096
#define T_LEN 2048
#define D_IN  10
#define OUT_N 30
#define CSTEP 32                        // timesteps per chunk
#define NCH   (T_LEN/CSTEP)             // 64 chunks
#define SMP_BLK 16                      // samples per block
#define ASTR  17                        // padded sample stride in abuf (floats)
#define XBUF_F (CSTEP*SMP_BLK*D_IN)     // 5120 floats = 20 KB per X buffer
#define ABUF_F (CSTEP*SMP_BLK*ASTR)     // 8704 floats = 34 KB per xacc buffer
#define NLDW  (XBUF_F/(2*64))           // width-4 loads per producer wave = 40
#define CH_BYTES (CSTEP*D_IN*4)         // global X advance per chunk = 1280 B

// async global->LDS, width 4 (per-lane arbitrary global addr, linear LDS dest)
#define GLD4(gptr, lptr) __builtin_amdgcn_global_load_lds( \
    (const __attribute__((address_space(1))) void*)(gptr),  \
    (__attribute__((address_space(3))) void*)(lptr), 4, 0, 0)

// DPP cross-lane move (VALU pipe). quad_perm broadcast k: ctrl=k*0x55.
// row_ror:N: ctrl=0x120+N -> dest lane i receives src lane (i-N) mod 16.
template<int CTRL>
__device__ __forceinline__ float dppf(float x) {
    return __int_as_float(
        __builtin_amdgcn_mov_dpp(__float_as_int(x), CTRL, 0xF, 0xF, true));
}

// raw v_exp_f32 (2^x)
__device__ __forceinline__ float fast_exp2(float x) {
#if __has_builtin(__builtin_amdgcn_exp2f)
    return __builtin_amdgcn_exp2f(x);
#else
    float r; asm("v_exp_f32 %0, %1" : "=v"(r) : "v"(x)); return r;
#endif
}

// Producer/consumer LSTM scan with 2-way cross-sample ILP in the consumer.
// Block = 256 threads = 4 waves: waves 0-1 consumers, waves 2-3 producers.
// 256 blocks -> 1 block/CU -> each wave gets its OWN SIMD.
// Each consumer 16-lane group runs TWO independent sample chains (A,B)
// interleaved in the instruction stream: chain B's instructions fill chain
// A's dependency-latency gaps (R8/R9 showed the wall = issue + unfillable
// chain stalls; a second chain is the only independent work available).
// Producers compute xacc = mneg*(W_ih x + b) for 2 samples per lane, one
// chunk ahead, into double-buffered padded LDS (stride 17 -> conflict-free).
// R11 fix: NLDW was 10 (kept R7's 4-wave divisor); with 2 producer waves it
// must be 40 -> only 1/4 of xbuf was staged -> NaN from uninit LDS.
// Within a 16-lane group (one DPP row): u=(lr>>2)&3, tau=lr&3, weight row
// rw = tau*4+u (PyTorch i,f,g,o). State pre-scaled: cs = -2log2(e)*c, so
// tanh(c)=2*rcp(1+exp2(cs))-1.
__launch_bounds__(256, 1)
__global__ void lstm_scan_kernel(const float* __restrict__ X,
                                 const float* __restrict__ W_ih,
                                 const float* __restrict__ W_hh,
                                 const float* __restrict__ b_ih,
                                 const float* __restrict__ b_hh,
                                 float* __restrict__ hT)
{
    __shared__ float xbuf[2][XBUF_F];   // 40 KB: X chunks [t][s][10]
    __shared__ float abuf[2][ABUF_F];   // 68 KB: xacc chunks [t][s][17(16 used)]

    const int tid  = threadIdx.x;
    const int lane = tid & 63;
    const int w    = tid >> 6;          // wave in block (0..3)
    const int lr   = lane & 15;         // position within 16-lane group
    const int u    = (lr >> 2) & 3;     // hidden unit
    const int tau  = lr & 3;            // 0=i,1=f,2=g,3=o
    const int rw   = tau * 4 + u;       // weight row
    const uint32_t samp0 = (uint32_t)blockIdx.x * SMP_BLK;

    const float KT = -2.8853900817779268f;   // -2*log2(e)
    const float KS = -1.4426950408889634f;   // -log2(e)
    const float mneg = (tau == 2) ? KT : KS;

    if (w >= 2) {
        // ---------------- PRODUCER (2 samples per lane) ----------------
        const int pw = w - 2;
        const int sp = lane >> 4;           // sample-pair slot (0..3)
        const int pA = pw * 8 + sp * 2;     // samples within block
        const int pB = pA + 1;
        float wih[10];
        #pragma unroll
        for (int d0 = 0; d0 < 10; ++d0) wih[d0] = W_ih[rw*10 + d0] * mneg;
        const float bsum = (b_ih[rw] + b_hh[rw]) * mneg;

        // staging offsets: element p = [t][s][d] within a chunk
        uint32_t voff[NLDW];
        #pragma unroll
        for (int kk = 0; kk < NLDW; ++kk) {
            int p   = (pw*NLDW + kk)*64 + lane;
            int t   = p / 160;          // D_IN*SMP_BLK = 160
            int rem = p - t*160;
            int s   = rem / 10;
            int d0  = rem - s*10;
            voff[kk] = (samp0 + (uint32_t)s) * (uint32_t)(T_LEN*D_IN*4)
                     + (uint32_t)(t*40 + d0*4);
        }
        const char* Xc = (const char*)X;

        // xproj of one chunk from xbuf[bb] -> abuf[bb], 2 samples per lane
        auto produce = [&](int bb) {
            #pragma unroll 4
            for (int t = 0; t < CSTEP; ++t) {
                const float2* xa = (const float2*)&xbuf[bb][(t*SMP_BLK + pA)*10];
                const float2* xb = (const float2*)&xbuf[bb][(t*SMP_BLK + pB)*10];
                float2 a0 = xa[0], a1 = xa[1], a2 = xa[2], a3 = xa[3], a4 = xa[4];
                float2 b0 = xb[0], b1 = xb[1], b2 = xb[2], b3 = xb[3], b4 = xb[4];
                float accA = bsum, accB = bsum;
                accA = fmaf(wih[0], a0.x, accA); accB = fmaf(wih[0], b0.x, accB);
                accA = fmaf(wih[1], a0.y, accA); accB = fmaf(wih[1], b0.y, accB);
                accA = fmaf(wih[2], a1.x, accA); accB = fmaf(wih[2], b1.x, accB);
                accA = fmaf(wih[3], a1.y, accA); accB = fmaf(wih[3], b1.y, accB);
                accA = fmaf(wih[4], a2.x, accA); accB = fmaf(wih[4], b2.x, accB);
                accA = fmaf(wih[5], a2.y, accA); accB = fmaf(wih[5], b2.y, accB);
                accA = fmaf(wih[6], a3.x, accA); accB = fmaf(wih[6], b3.x, accB);
                accA = fmaf(wih[7], a3.y, accA); accB = fmaf(wih[7], b3.y, accB);
                accA = fmaf(wih[8], a4.x, accA); accB = fmaf(wih[8], b4.x, accB);
                accA = fmaf(wih[9], a4.y, accA); accB = fmaf(wih[9], b4.y, accB);
                abuf[bb][(t*SMP_BLK + pA)*ASTR + lr] = accA;
                abuf[bb][(t*SMP_BLK + pB)*ASTR + lr] = accB;
            }
        };

        // prologue: stage X(0)
        #pragma unroll
        for (int kk = 0; kk < NLDW; ++kk)
            GLD4(Xc + voff[kk], &xbuf[0][(pw*NLDW+kk)*64]);
        __syncthreads();                               // (1) X0 ready
        // stage X(1) (flies during compute), compute xacc(0)
        #pragma unroll
        for (int kk = 0; kk < NLDW; ++kk)
            GLD4(Xc + (voff[kk] + CH_BYTES), &xbuf[1][(pw*NLDW+kk)*64]);
        produce(0);
        __syncthreads();                               // (2) A0 + X1 ready

        for (int k = 0; k < NCH; ++k) {
            if (k + 1 < NCH) {
                if (k + 2 < NCH) {
                    const uint32_t add = (uint32_t)(k+2) * CH_BYTES;
                    #pragma unroll
                    for (int kk = 0; kk < NLDW; ++kk)
                        GLD4(Xc + (voff[kk] + add),
                             &xbuf[k&1][(pw*NLDW+kk)*64]);
                }
                produce((k+1)&1);
            }
            __syncthreads();
        }
    } else {
        // ---------------- CONSUMER (2 chains per 16-lane group) ----------
        __builtin_amdgcn_s_setprio(1);
        const int grp = lane >> 4;          // group slot (0..3)
        const int sgA = w * 8 + grp * 2;    // sample within block, chain A
        const int sgB = sgA + 1;            // chain B
        //   tau=0 (i): a = KT*sigmoid   tau=1 (f): a = sigmoid
        //   tau=2 (g): a = tanh         tau=3 (o): a = 2*sigmoid
        const float k1 = (tau == 0) ? KT : ((tau == 1) ? 1.0f : 2.0f);
        const float k0 = (tau == 2) ? -1.0f : 0.0f;
        // rotated W_hh columns to match row_ror data placement
        const float whhA = W_hh[rw*4 +  u        ] * mneg;
        const float whhB = W_hh[rw*4 + ((u+3)&3)] * mneg;
        const float whhC = W_hh[rw*4 + ((u+2)&3)] * mneg;
        const float whhD = W_hh[rw*4 + ((u+1)&3)] * mneg;

        __syncthreads();                               // (1)
        __syncthreads();                               // (2)

        float csA = 0.f, hsA = 0.f;
        float csB = 0.f, hsB = 0.f;
        for (int k = 0; k < NCH; ++k) {
            const float* aA = &abuf[k&1][sgA*ASTR + lr];
            const float* aB = &abuf[k&1][sgB*ASTR + lr];
            #pragma unroll
            for (int t = 0; t < CSTEP; ++t) {
                float xA = aA[t*(SMP_BLK*ASTR)];
                float xB = aB[t*(SMP_BLK*ASTR)];
                // two independent chains, interleaved
                float hBA = dppf<0x124>(hsA);   float hBB = dppf<0x124>(hsB);
                float hCA = dppf<0x128>(hsA);   float hCB = dppf<0x128>(hsB);
                float hDA = dppf<0x12C>(hsA);   float hDB = dppf<0x12C>(hsB);
                float u1A = fmaf(whhA, hsA, xA);
                float u1B = fmaf(whhA, hsB, xB);
                float acA = fmaf(whhB, hBA, u1A) + fmaf(whhD, hDA, whhC * hCA);
                float acB = fmaf(whhB, hBB, u1B) + fmaf(whhD, hDB, whhC * hCB);
                float eA  = fast_exp2(acA);
                float eB  = fast_exp2(acB);
                float aAv = fmaf(k1, __builtin_amdgcn_rcpf(1.0f + eA), k0);
                float aBv = fmaf(k1, __builtin_amdgcn_rcpf(1.0f + eB), k0);
                float giA = dppf<0x00>(aAv);    float giB = dppf<0x00>(aBv);
                float gfA = dppf<0x55>(aAv);    float gfB = dppf<0x55>(aBv);
                float ggA = dppf<0xAA>(aAv);    float ggB = dppf<0xAA>(aBv);
                float goA = dppf<0xFF>(aAv);    float goB = dppf<0xFF>(aBv);
                float mgoA = -0.5f * goA;       float mgoB = -0.5f * goB;
                csA = fmaf(gfA, csA, giA * ggA);
                csB = fmaf(gfB, csB, giB * ggB);
                float e2A = fast_exp2(csA);
                float e2B = fast_exp2(csB);
                float r2A = __builtin_amdgcn_rcpf(1.0f + e2A);
                float r2B = __builtin_amdgcn_rcpf(1.0f + e2B);
                hsA = fmaf(goA, r2A, mgoA);
                hsB = fmaf(goB, r2B, mgoB);
            }
            __syncthreads();
        }
        if (tau == 0) {
            hT[(samp0 + sgA)*4 + u] = hsA;
            hT[(samp0 + sgB)*4 + u] = hsB;
        }
    }
}

// Head: logits = hT @ W_out^T + b_out, then softmax. One thread per sample.
__global__ void head_kernel(const float* __restrict__ hT,
                            const float* __restrict__ W_out,
                            const float* __restrict__ b_out,
                            float* __restrict__ out)
{
    int b = blockIdx.x * blockDim.x + threadIdx.x;
    if (b >= B_TOT) return;
    float4 h = ((const float4*)hT)[b];
    float lg[OUT_N];
    float m = -1e30f;
    #pragma unroll
    for (int o = 0; o < OUT_N; ++o) {
        float v = b_out[o];
        v = fmaf(W_out[o*4+0], h.x, v);
        v = fmaf(W_out[o*4+1], h.y, v);
        v = fmaf(W_out[o*4+2], h.z, v);
        v = fmaf(W_out[o*4+3], h.w, v);
        lg[o] = v;
        m = fmaxf(m, v);
    }
    float s = 0.f;
    #pragma unroll
    for (int o = 0; o < OUT_N; ++o) {
        float e = fast_exp2((lg[o] - m) * 1.4426950408889634f);
        lg[o] = e;
        s += e;
    }
    float rs = 1.0f / s;
    #pragma unroll
    for (int o = 0; o < OUT_N; ++o) out[(size_t)b*OUT_N + o] = lg[o] * rs;
}

extern "C" void kernel_launch(void* const* d_in, const int* in_sizes, int n_in,
                              void* d_out, int out_size, void* d_ws, size_t ws_size,
                              hipStream_t stream)
{
    const float* X     = (const float*)d_in[0];
    const float* W_ih  = (const float*)d_in[1];
    const float* W_hh  = (const float*)d_in[2];
    const float* b_ih  = (const float*)d_in[3];
    const float* b_hh  = (const float*)d_in[4];
    const float* W_out = (const float*)d_in[5];
    const float* b_out = (const float*)d_in[6];
    float* out = (float*)d_out;
    float* hTs = (float*)d_ws;   // 4096*4 floats = 64 KB scratch

    lstm_scan_kernel<<<B_TOT/SMP_BLK, 256, 0, stream>>>(X, W_ih, W_hh, b_ih, b_hh, hTs);
    head_kernel<<<B_TOT/256, 256, 0, stream>>>(hTs, W_out, b_out, out);
}